// Round 6
// baseline (341.857 us; speedup 1.0000x reference)
//
#include <hip/hip_runtime.h>
#include <math.h>

#define D 128
#define EPSV 1e-5f

typedef unsigned short ushort_t;
typedef __attribute__((ext_vector_type(8))) short short8v;
typedef __attribute__((ext_vector_type(4))) float f32x4;

__device__ __forceinline__ float bf2f(unsigned u) {
    return __uint_as_float(u << 16);
}
__device__ __forceinline__ ushort_t f2bf(float f) {
    unsigned u = __float_as_uint(f);
    unsigned r = (u + 0x7fffu + ((u >> 16) & 1u)) >> 16;   // RNE
    return (ushort_t)r;
}
__device__ __forceinline__ float bfp(uint4 v, int i) {   // bf16 element i of 8
    unsigned w = (&v.x)[i >> 1];
    return bf2f((i & 1) ? (w >> 16) : (w & 0xffffu));
}

// ============ projection GEMM: [qt(512) | xr(128)] = x @ wt_all; also emits xbf ============
// wt_all[c][k]: c<512 -> combined Wqk (c = h*128+d), c>=512 -> w_skip col (c-512).
// grid (MB, 2): y=0 does col-tiles 0-2 (+ xbf store), y=1 does 3-4.
__global__ __launch_bounds__(256)
void proj_gemm(const float* __restrict__ x,
               const ushort_t* __restrict__ Bt,   // wt_all [640][128]
               const float* __restrict__ bias,    // [640]
               ushort_t* __restrict__ qtb,        // [M][512]
               ushort_t* __restrict__ xrb,        // [M][128]
               ushort_t* __restrict__ xbf,        // [M][128]
               int M)
{
    __shared__ ushort_t Cs[128 * 136];
    const int tid = threadIdx.x, lane = tid & 63, wid = tid >> 6;
    const int wr = wid >> 1, wc = wid & 1;
    const int R0 = blockIdx.x * 128;
    const int cbeg = blockIdx.y ? 3 : 0;
    const int cend = blockIdx.y ? 5 : 3;

    short8v av[4][4];                         // [r][ks], bf16 converted from f32 x
    #pragma unroll
    for (int r = 0; r < 4; ++r) {
        int gr = R0 + wr * 64 + r * 16 + (lane & 15);
        if (gr >= M) gr = M - 1;
        const float* xrow = x + (size_t)gr * 128 + (lane >> 4) * 8;
        #pragma unroll
        for (int ks = 0; ks < 4; ++ks) {
            float4 lo = *reinterpret_cast<const float4*>(xrow + ks * 32);
            float4 hi = *reinterpret_cast<const float4*>(xrow + ks * 32 + 4);
            short8v a;
            a[0] = (short)f2bf(lo.x); a[1] = (short)f2bf(lo.y);
            a[2] = (short)f2bf(lo.z); a[3] = (short)f2bf(lo.w);
            a[4] = (short)f2bf(hi.x); a[5] = (short)f2bf(hi.y);
            a[6] = (short)f2bf(hi.z); a[7] = (short)f2bf(hi.w);
            av[r][ks] = a;
        }
    }

    if (blockIdx.y == 0) {                    // emit x in bf16 for the edge gather
        #pragma unroll
        for (int r = 0; r < 4; ++r) {
            int gr = R0 + wr * 64 + r * 16 + (lane & 15);
            if (gr < M) {
                #pragma unroll
                for (int ks = 0; ks < 4; ++ks)
                    *reinterpret_cast<short8v*>(
                        &xbf[(size_t)gr * 128 + ks * 32 + (lane >> 4) * 8]) = av[r][ks];
            }
        }
    }

    for (int ct = cbeg; ct < cend; ++ct) {
        f32x4 acc[4][4] = {};
        #pragma unroll
        for (int ks = 0; ks < 4; ++ks) {
            short8v bv[4];
            #pragma unroll
            for (int c = 0; c < 4; ++c) {
                int col = ct * 128 + wc * 64 + c * 16 + (lane & 15);
                bv[c] = *reinterpret_cast<const short8v*>(
                    &Bt[(size_t)col * 128 + ks * 32 + (lane >> 4) * 8]);
            }
            #pragma unroll
            for (int r = 0; r < 4; ++r)
                #pragma unroll
                for (int c = 0; c < 4; ++c)
                    acc[r][c] = __builtin_amdgcn_mfma_f32_16x16x32_bf16(av[r][ks], bv[c], acc[r][c], 0, 0, 0);
        }
        __syncthreads();                      // Cs free from previous ct
        #pragma unroll
        for (int r = 0; r < 4; ++r) {
            int rowb = wr * 64 + r * 16 + (lane >> 4) * 4;
            #pragma unroll
            for (int i = 0; i < 4; ++i)
                #pragma unroll
                for (int c = 0; c < 4; ++c) {
                    int col = wc * 64 + c * 16 + (lane & 15);
                    Cs[(rowb + i) * 136 + col] = f2bf(acc[r][c][i] + bias[ct * 128 + col]);
                }
        }
        __syncthreads();
        #pragma unroll
        for (int it = 0; it < 8; ++it) {      // 128 rows x 16 chunks of 16B
            int linear = tid + it * 256;
            int row = linear >> 4, ch = linear & 15;
            int gr = R0 + row;
            if (gr < M) {
                uint4 v = *reinterpret_cast<const uint4*>(&Cs[row * 136 + ch * 8]);
                ushort_t* dst;
                if (ct < 4) dst = qtb + (size_t)gr * 512 + ct * 128;
                else        dst = xrb + (size_t)gr * 128;
                *reinterpret_cast<uint4*>(dst + ch * 8) = v;
            }
        }
    }
}

// ===== edge kernel: gathers ONLY x rows; aggregates per-head attn-x and gcn-x =====
// agg row [640] bf16 = [attn-agg h=0..3 (4x128, normalized) | gcn-agg (128)]
__global__ __launch_bounds__(256)
void edge_fused_kernel(const ushort_t* __restrict__ xbf,
                       const ushort_t* __restrict__ qtb,
                       const int* __restrict__ row_start,
                       const int* __restrict__ csr_src,
                       const float* __restrict__ dinv,
                       ushort_t* __restrict__ agg,     // [N][640]
                       float* __restrict__ flag,       // [N]
                       int n)
{
    const int wid = threadIdx.x >> 6, lane = threadIdx.x & 63;
    const int node = blockIdx.x * 4 + wid;
    if (node >= n) return;
    const int slot = lane >> 4, li = lane & 15;
    const int d8 = li * 8;

    float qf[4][8];                            // qt fragments, all 4 heads
    #pragma unroll
    for (int h = 0; h < 4; ++h) {
        uint4 qu = *reinterpret_cast<const uint4*>(&qtb[(size_t)node * 512 + h * 128 + d8]);
        #pragma unroll
        for (int i = 0; i < 8; ++i) qf[h][i] = bfp(qu, i);
    }

    const int e0 = row_start[node], e1 = row_start[node + 1];
    const float dn = dinv[node];
    const float scale = 0.17677669529663687f;  // 1/sqrt(32)

    float sh[4] = {}, va[4][8] = {}, ga[8] = {};

    for (int j = e0; j < e1; j += 4) {
        const int je = j + slot;
        const bool act = je < e1;
        const int sidx = act ? csr_src[je] : 0;
        uint4 xu = *reinterpret_cast<const uint4*>(&xbf[(size_t)sidx * 128 + d8]);
        float xv[8];
        #pragma unroll
        for (int i = 0; i < 8; ++i) xv[i] = bfp(xu, i);
        float p[4];
        #pragma unroll
        for (int h = 0; h < 4; ++h) {
            float t = 0.f;
            #pragma unroll
            for (int i = 0; i < 8; ++i) t = fmaf(qf[h][i], xv[i], t);
            t += __shfl_xor(t, 1);             // reduce over the slot's 16 lanes
            t += __shfl_xor(t, 2);
            t += __shfl_xor(t, 4);
            t += __shfl_xor(t, 8);
            p[h] = t;
        }
        const float c = act ? dn * dinv[sidx] : 0.f;
        #pragma unroll
        for (int h = 0; h < 4; ++h) {
            float w = act ? __expf(p[h] * scale) : 0.f;
            sh[h] += w;
            #pragma unroll
            for (int i = 0; i < 8; ++i) va[h][i] = fmaf(w, xv[i], va[h][i]);
        }
        #pragma unroll
        for (int i = 0; i < 8; ++i) ga[i] = fmaf(c, xv[i], ga[i]);
    }
    // combine the 4 slots (butterfly over lane bits 4,5)
    #pragma unroll
    for (int off = 16; off <= 32; off <<= 1) {
        #pragma unroll
        for (int h = 0; h < 4; ++h) {
            sh[h] += __shfl_xor(sh[h], off);
            #pragma unroll
            for (int i = 0; i < 8; ++i) va[h][i] += __shfl_xor(va[h][i], off);
        }
        #pragma unroll
        for (int i = 0; i < 8; ++i) ga[i] += __shfl_xor(ga[i], off);
    }

    if (slot == 0) {
        #pragma unroll
        for (int h = 0; h < 4; ++h) {
            float r = 1.f / fmaxf(sh[h], 1e-16f);
            uint4 o;
            #pragma unroll
            for (int i = 0; i < 4; ++i)
                (&o.x)[i] = (unsigned)f2bf(va[h][2 * i] * r)
                          | ((unsigned)f2bf(va[h][2 * i + 1] * r) << 16);
            *reinterpret_cast<uint4*>(&agg[(size_t)node * 640 + h * 128 + d8]) = o;
        }
        uint4 og;
        #pragma unroll
        for (int i = 0; i < 4; ++i)
            (&og.x)[i] = (unsigned)f2bf(ga[2 * i]) | ((unsigned)f2bf(ga[2 * i + 1]) << 16);
        *reinterpret_cast<uint4*>(&agg[(size_t)node * 640 + 512 + d8]) = og;
        if (li == 0) flag[node] = (sh[0] > 0.f) ? 1.f : 0.f;
    }
}

// ===== combine: og = aggA@Wv + flag*bv, local = aggG@Wgcn + b_gcn; beta gate; LN1 =====
// wt_vg[c][k]: c<128 -> wv[k][c], c>=128 -> wgcn[k][c-128]
__global__ __launch_bounds__(256)
void combine_ln1(const ushort_t* __restrict__ agg,     // [M][640]
                 const ushort_t* __restrict__ wt_vg,   // [256][128]
                 const float* __restrict__ bvv, const float* __restrict__ b_gcn,
                 const float* __restrict__ flag,
                 const ushort_t* __restrict__ xrb,
                 const float* __restrict__ w_beta,     // [384]
                 const float* __restrict__ g1, const float* __restrict__ b1,
                 const float* __restrict__ local_w, const float* __restrict__ global_w,
                 ushort_t* __restrict__ hln_bf, int M)
{
    __shared__ float OgS[128 * 130];
    __shared__ float LoS[128 * 130];
    const int tid = threadIdx.x, lane = tid & 63, wid = tid >> 6;
    const int wr = wid >> 1, wc = wid & 1;
    const int R0 = blockIdx.x * 128;

    // ---- og: this wave covers cols wc*64 .. wc*64+63 = heads {wc*2, wc*2+1} ----
    {
        f32x4 acc[4][4] = {};
        #pragma unroll
        for (int hl = 0; hl < 2; ++hl) {
            const int head = wc * 2 + hl;
            short8v av[4][4];
            #pragma unroll
            for (int r = 0; r < 4; ++r) {
                int gr = R0 + wr * 64 + r * 16 + (lane & 15);
                if (gr >= M) gr = M - 1;
                #pragma unroll
                for (int ks = 0; ks < 4; ++ks)
                    av[r][ks] = *reinterpret_cast<const short8v*>(
                        &agg[(size_t)gr * 640 + head * 128 + ks * 32 + (lane >> 4) * 8]);
            }
            #pragma unroll
            for (int cfl = 0; cfl < 2; ++cfl) {
                const int cf = hl * 2 + cfl;
                const int col = wc * 64 + cf * 16 + (lane & 15);
                #pragma unroll
                for (int ks = 0; ks < 4; ++ks) {
                    short8v bfrag = *reinterpret_cast<const short8v*>(
                        &wt_vg[(size_t)col * 128 + ks * 32 + (lane >> 4) * 8]);
                    #pragma unroll
                    for (int r = 0; r < 4; ++r)
                        acc[r][cf] = __builtin_amdgcn_mfma_f32_16x16x32_bf16(av[r][ks], bfrag, acc[r][cf], 0, 0, 0);
                }
            }
        }
        #pragma unroll
        for (int r = 0; r < 4; ++r) {
            int rowb = wr * 64 + r * 16 + (lane >> 4) * 4;
            #pragma unroll
            for (int i = 0; i < 4; ++i)
                #pragma unroll
                for (int cf = 0; cf < 4; ++cf)
                    OgS[(rowb + i) * 130 + wc * 64 + cf * 16 + (lane & 15)] = acc[r][cf][i];
        }
    }
    // ---- local: aggG (cols 512..639) @ Wgcn ----
    {
        f32x4 acc[4][4] = {};
        short8v av[4][4];
        #pragma unroll
        for (int r = 0; r < 4; ++r) {
            int gr = R0 + wr * 64 + r * 16 + (lane & 15);
            if (gr >= M) gr = M - 1;
            #pragma unroll
            for (int ks = 0; ks < 4; ++ks)
                av[r][ks] = *reinterpret_cast<const short8v*>(
                    &agg[(size_t)gr * 640 + 512 + ks * 32 + (lane >> 4) * 8]);
        }
        #pragma unroll
        for (int ks = 0; ks < 4; ++ks) {
            short8v bfrag[4];
            #pragma unroll
            for (int cf = 0; cf < 4; ++cf) {
                int col = wc * 64 + cf * 16 + (lane & 15);
                bfrag[cf] = *reinterpret_cast<const short8v*>(
                    &wt_vg[(size_t)(128 + col) * 128 + ks * 32 + (lane >> 4) * 8]);
            }
            #pragma unroll
            for (int r = 0; r < 4; ++r)
                #pragma unroll
                for (int cf = 0; cf < 4; ++cf)
                    acc[r][cf] = __builtin_amdgcn_mfma_f32_16x16x32_bf16(av[r][ks], bfrag[cf], acc[r][cf], 0, 0, 0);
        }
        #pragma unroll
        for (int r = 0; r < 4; ++r) {
            int rowb = wr * 64 + r * 16 + (lane >> 4) * 4;
            #pragma unroll
            for (int i = 0; i < 4; ++i)
                #pragma unroll
                for (int cf = 0; cf < 4; ++cf)
                    LoS[(rowb + i) * 130 + wc * 64 + cf * 16 + (lane & 15)] = acc[r][cf][i];
        }
    }
    __syncthreads();

    // ---- per-row: bias, beta gate, combine, LN1 ----
    const int d0 = lane * 2, d1 = d0 + 1;
    const float lw = local_w[0], gw = global_w[0];
    const float bv0 = bvv[d0], bv1 = bvv[d1];
    const float bg0 = b_gcn[d0], bg1 = b_gcn[d1];
    const float wb00 = w_beta[d0],       wb01 = w_beta[d1];
    const float wb10 = w_beta[128 + d0], wb11 = w_beta[128 + d1];
    const float wb20 = w_beta[256 + d0], wb21 = w_beta[256 + d1];
    const float g1a = g1[d0], g1b = g1[d1], b1a = b1[d0], b1b = b1[d1];

    for (int rr = 0; rr < 32; ++rr) {
        int row = wid * 32 + rr;
        int gr = R0 + row;
        if (gr >= M) break;
        const float fl = flag[gr];
        float og0 = OgS[row * 130 + d0] + fl * bv0;
        float og1 = OgS[row * 130 + d1] + fl * bv1;
        float lo0 = LoS[row * 130 + d0] + bg0;
        float lo1 = LoS[row * 130 + d1] + bg1;
        unsigned xu = *reinterpret_cast<const unsigned*>(&xrb[(size_t)gr * 128 + d0]);
        float xr0 = bf2f(xu & 0xffffu), xr1 = bf2f(xu >> 16);

        float part = og0 * wb00 + og1 * wb01 + xr0 * wb10 + xr1 * wb11
                   + (og0 - xr0) * wb20 + (og1 - xr1) * wb21;
        #pragma unroll
        for (int off = 1; off <= 32; off <<= 1) part += __shfl_xor(part, off);
        const float beta = 1.f / (1.f + __expf(-part));

        float go0 = beta * xr0 + (1.f - beta) * og0;
        float go1 = beta * xr1 + (1.f - beta) * og1;
        float t0 = 2.f * (lw * lo0 + gw * go0);
        float t1 = 2.f * (lw * lo1 + gw * go1);

        float ssum = t0 + t1;
        #pragma unroll
        for (int off = 1; off <= 32; off <<= 1) ssum += __shfl_xor(ssum, off);
        float mu = ssum * (1.f / 128.f);
        float dv0 = t0 - mu, dv1 = t1 - mu;
        float vsum = dv0 * dv0 + dv1 * dv1;
        #pragma unroll
        for (int off = 1; off <= 32; off <<= 1) vsum += __shfl_xor(vsum, off);
        float rs = rsqrtf(vsum * (1.f / 128.f) + EPSV);
        float o0 = dv0 * rs * g1a + b1a;
        float o1 = dv1 * rs * g1b + b1b;
        *reinterpret_cast<unsigned*>(&hln_bf[(size_t)gr * 128 + d0]) =
            (unsigned)f2bf(o0) | ((unsigned)f2bf(o1) << 16);
    }
}

// ============ fused FFN1 + FFN2 + residual + LayerNorm2 -> f32 out ============
__device__ __forceinline__ int swz(int ch, int row) {
    return (ch & 24) | ((ch ^ row) & 7);
}

__global__ __launch_bounds__(256)
void ffn_fused(const ushort_t* __restrict__ hlnb,     // [M][128] bf16
               const ushort_t* __restrict__ wt_rel,   // [256][128] bf16
               const ushort_t* __restrict__ wt_root,  // [128][256] bf16
               const float* __restrict__ g2, const float* __restrict__ b2,
               float* __restrict__ outf, int M)
{
    __shared__ float smem[128 * 130];                 // 66.6 KB
    ushort_t* Hs = (ushort_t*)smem;                   // hidden bf16 [128][256] swizzled
    const int tid = threadIdx.x, lane = tid & 63, wid = tid >> 6;
    const int wr = wid >> 1, wc = wid & 1;
    const int R0 = blockIdx.x * 128;

    short8v av[4][4];
    #pragma unroll
    for (int r = 0; r < 4; ++r) {
        int gr = R0 + wr * 64 + r * 16 + (lane & 15);
        if (gr >= M) gr = M - 1;
        #pragma unroll
        for (int ks = 0; ks < 4; ++ks)
            av[r][ks] = *reinterpret_cast<const short8v*>(
                &hlnb[(size_t)gr * 128 + ks * 32 + (lane >> 4) * 8]);
    }
    for (int ct = 0; ct < 2; ++ct) {
        f32x4 acc[4][4] = {};
        #pragma unroll
        for (int ks = 0; ks < 4; ++ks) {
            short8v bv[4];
            #pragma unroll
            for (int c = 0; c < 4; ++c) {
                int col = ct * 128 + wc * 64 + c * 16 + (lane & 15);
                bv[c] = *reinterpret_cast<const short8v*>(
                    &wt_rel[(size_t)col * 128 + ks * 32 + (lane >> 4) * 8]);
            }
            #pragma unroll
            for (int r = 0; r < 4; ++r)
                #pragma unroll
                for (int c = 0; c < 4; ++c)
                    acc[r][c] = __builtin_amdgcn_mfma_f32_16x16x32_bf16(av[r][ks], bv[c], acc[r][c], 0, 0, 0);
        }
        #pragma unroll
        for (int r = 0; r < 4; ++r) {
            int rowb = wr * 64 + r * 16 + (lane >> 4) * 4;
            #pragma unroll
            for (int i = 0; i < 4; ++i)
                #pragma unroll
                for (int c = 0; c < 4; ++c) {
                    int row = rowb + i;
                    int col = ct * 128 + wc * 64 + c * 16 + (lane & 15);
                    int ch = col >> 3, el = col & 7;
                    Hs[row * 256 + swz(ch, row) * 8 + el] = f2bf(fmaxf(acc[r][c][i], 0.f));
                }
        }
    }
    __syncthreads();

    f32x4 acc2[4][4] = {};
    #pragma unroll
    for (int ks = 0; ks < 8; ++ks) {
        short8v a2[4], bv[4];
        #pragma unroll
        for (int r = 0; r < 4; ++r) {
            int row = wr * 64 + r * 16 + (lane & 15);
            int ch = ks * 4 + (lane >> 4);
            a2[r] = *reinterpret_cast<const short8v*>(&Hs[row * 256 + swz(ch, row) * 8]);
        }
        #pragma unroll
        for (int c = 0; c < 4; ++c) {
            int col = wc * 64 + c * 16 + (lane & 15);
            bv[c] = *reinterpret_cast<const short8v*>(
                &wt_root[(size_t)col * 256 + ks * 32 + (lane >> 4) * 8]);
        }
        #pragma unroll
        for (int r = 0; r < 4; ++r)
            #pragma unroll
            for (int c = 0; c < 4; ++c)
                acc2[r][c] = __builtin_amdgcn_mfma_f32_16x16x32_bf16(a2[r], bv[c], acc2[r][c], 0, 0, 0);
    }
    __syncthreads();                          // hidden reads done; reuse as f32 C

    float* Cs = smem;                         // [128][130]
    #pragma unroll
    for (int r = 0; r < 4; ++r) {
        int rowb = wr * 64 + r * 16 + (lane >> 4) * 4;
        #pragma unroll
        for (int i = 0; i < 4; ++i)
            #pragma unroll
            for (int c = 0; c < 4; ++c)
                Cs[(rowb + i) * 130 + wc * 64 + c * 16 + (lane & 15)] = acc2[r][c][i];
    }
    __syncthreads();

    const float ga = g2[lane * 2], gb = g2[lane * 2 + 1];
    const float ba = b2[lane * 2], bb2 = b2[lane * 2 + 1];
    for (int rr = 0; rr < 32; ++rr) {
        int row = wid * 32 + rr;
        int gr = R0 + row;
        if (gr >= M) break;
        unsigned hu = *reinterpret_cast<const unsigned*>(&hlnb[(size_t)gr * 128 + lane * 2]);
        float t0 = Cs[row * 130 + lane * 2]     + bf2f(hu & 0xffffu);
        float t1 = Cs[row * 130 + lane * 2 + 1] + bf2f(hu >> 16);
        float ssum = t0 + t1;
        #pragma unroll
        for (int off = 1; off <= 32; off <<= 1) ssum += __shfl_xor(ssum, off);
        float mu = ssum * (1.f / 128.f);
        float dv0 = t0 - mu, dv1 = t1 - mu;
        float vsum = dv0 * dv0 + dv1 * dv1;
        #pragma unroll
        for (int off = 1; off <= 32; off <<= 1) vsum += __shfl_xor(vsum, off);
        float rs = rsqrtf(vsum * (1.f / 128.f) + EPSV);
        float2 o = make_float2(dv0 * rs * ga + ba, dv1 * rs * gb + bb2);
        *reinterpret_cast<float2*>(&outf[(size_t)gr * 128 + lane * 2]) = o;
    }
}

// =================== weight packing ===================
// wt_all[640][128]: c<512 -> Wqk combined (c=h*128+d): sum_j wq[k][h32+j]*wk[d][h32+j]
//                   c>=512 -> wsk[k][c-512]
// bias_all[640]:    c<512 -> sum_j bq[h32+j]*wk[d][h32+j] ; c>=512 -> bsk
// wt_vg[256][128]:  c<128 -> wv[k][c] ; else wgcn[k][c-128]
__global__ void pack_weights_kernel(const float* __restrict__ wg, const float* __restrict__ wq,
                                    const float* __restrict__ wk, const float* __restrict__ wv,
                                    const float* __restrict__ wsk,
                                    const float* __restrict__ bq, const float* __restrict__ bsk,
                                    const float* __restrict__ wrel, const float* __restrict__ wroot,
                                    ushort_t* __restrict__ wt_all, ushort_t* __restrict__ wt_vg,
                                    ushort_t* __restrict__ wt_rel, ushort_t* __restrict__ wt_root,
                                    float* __restrict__ bias_all)
{
    int i = blockIdx.x * 256 + threadIdx.x;
    if (i < 640 * 128) {
        int c = i >> 7, k = i & 127;
        float v;
        if (c < 512) {
            int h = c >> 7, d = c & 127;
            float acc = 0.f;
            #pragma unroll
            for (int j = 0; j < 32; ++j)
                acc = fmaf(wq[k * 128 + h * 32 + j], wk[d * 128 + h * 32 + j], acc);
            v = acc;
        } else {
            v = wsk[k * 128 + (c - 512)];
        }
        wt_all[i] = f2bf(v);
    } else if (i < 640 * 128 + 640) {
        int c = i - 640 * 128;
        float b;
        if (c < 512) {
            int h = c >> 7, d = c & 127;
            float acc = 0.f;
            #pragma unroll
            for (int j = 0; j < 32; ++j)
                acc = fmaf(bq[h * 32 + j], wk[d * 128 + h * 32 + j], acc);
            b = acc;
        } else {
            b = bsk[c - 512];
        }
        bias_all[c] = b;
    } else if (i < 640 * 128 + 640 + 256 * 128) {
        int j = i - (640 * 128 + 640);
        int c = j >> 7, k = j & 127;
        wt_vg[j] = f2bf(c < 128 ? wv[k * 128 + c] : wg[k * 128 + (c - 128)]);
    } else if (i < 640 * 128 + 640 + 2 * 256 * 128) {
        int j = i - (640 * 128 + 640 + 256 * 128);
        int c = j >> 7, k = j & 127;
        wt_rel[j] = f2bf(wrel[k * 256 + c]);
    } else if (i < 640 * 128 + 640 + 2 * 256 * 128 + 128 * 256) {
        int j = i - (640 * 128 + 640 + 2 * 256 * 128);
        int c = j >> 8, k = j & 255;
        wt_root[j] = f2bf(wroot[k * 128 + c]);
    }
}

// =================== graph prep ===================
__global__ void deg_count_kernel(const int* __restrict__ dst, int* __restrict__ deg, int E)
{
    int e = blockIdx.x * blockDim.x + threadIdx.x;
    if (e < E) atomicAdd(&deg[dst[e]], 1);
}

__global__ __launch_bounds__(256)
void scan1_kernel(const int* __restrict__ deg, int* __restrict__ row_start,
                  int* __restrict__ bsum, int n)
{
    __shared__ int ws[4];
    const int t = threadIdx.x, lane = t & 63, wid = t >> 6;
    const int base = blockIdx.x * 1024 + t * 4;
    int v0 = 0, v1 = 0, v2 = 0, v3 = 0;
    if (base + 3 < n) {
        int4 q = *reinterpret_cast<const int4*>(&deg[base]);
        v0 = q.x; v1 = q.y; v2 = q.z; v3 = q.w;
    } else {
        if (base < n)     v0 = deg[base];
        if (base + 1 < n) v1 = deg[base + 1];
        if (base + 2 < n) v2 = deg[base + 2];
        if (base + 3 < n) v3 = deg[base + 3];
    }
    int tot = v0 + v1 + v2 + v3;
    int inc = tot;
    #pragma unroll
    for (int off = 1; off < 64; off <<= 1) {
        int y = __shfl_up(inc, off);
        if (lane >= off) inc += y;
    }
    if (lane == 63) ws[wid] = inc;
    __syncthreads();
    int woff = 0;
    for (int w = 0; w < wid; ++w) woff += ws[w];
    int excl = woff + inc - tot;
    if (base < n)     row_start[base]     = excl;
    if (base + 1 < n) row_start[base + 1] = excl + v0;
    if (base + 2 < n) row_start[base + 2] = excl + v0 + v1;
    if (base + 3 < n) row_start[base + 3] = excl + v0 + v1 + v2;
    if (t == 0) bsum[blockIdx.x] = ws[0] + ws[1] + ws[2] + ws[3];
}

__global__ __launch_bounds__(256)
void scan2_kernel(int* __restrict__ bsum, int nb)
{
    __shared__ int ws[4];
    const int t = threadIdx.x, lane = t & 63, wid = t >> 6;
    const int base = t * 4;
    int v0 = 0, v1 = 0, v2 = 0, v3 = 0;
    if (base < nb)     v0 = bsum[base];
    if (base + 1 < nb) v1 = bsum[base + 1];
    if (base + 2 < nb) v2 = bsum[base + 2];
    if (base + 3 < nb) v3 = bsum[base + 3];
    int tot = v0 + v1 + v2 + v3;
    int inc = tot;
    #pragma unroll
    for (int off = 1; off < 64; off <<= 1) {
        int y = __shfl_up(inc, off);
        if (lane >= off) inc += y;
    }
    if (lane == 63) ws[wid] = inc;
    __syncthreads();
    int woff = 0;
    for (int w = 0; w < wid; ++w) woff += ws[w];
    int excl = woff + inc - tot;
    if (base < nb)     bsum[base]     = excl;
    if (base + 1 < nb) bsum[base + 1] = excl + v0;
    if (base + 2 < nb) bsum[base + 2] = excl + v0 + v1;
    if (base + 3 < nb) bsum[base + 3] = excl + v0 + v1 + v2;
}

__global__ void scan3_kernel(const int* __restrict__ deg, const int* __restrict__ bsum,
                             int* __restrict__ row_start, int* __restrict__ cursor,
                             float* __restrict__ dinv, int n, int E)
{
    int i = blockIdx.x * blockDim.x + threadIdx.x;
    if (i < n) {
        int rs = row_start[i] + bsum[i >> 10];
        row_start[i] = rs;
        cursor[i] = rs;
        int d = deg[i];
        dinv[i] = (d > 0) ? rsqrtf((float)d) : 0.f;
    }
    if (i == 0) row_start[n] = E;
}

__global__ void fill_kernel(const int* __restrict__ src, const int* __restrict__ dst,
                            int* __restrict__ cursor, int* __restrict__ csr_src, int E)
{
    int e = blockIdx.x * blockDim.x + threadIdx.x;
    if (e < E) {
        int d = dst[e];
        int pos = atomicAdd(&cursor[d], 1);
        csr_src[pos] = src[e];
    }
}

// =================== launch ===================
extern "C" void kernel_launch(void* const* d_in, const int* in_sizes, int n_in,
                              void* d_out, int out_size, void* d_ws, size_t ws_size,
                              hipStream_t stream)
{
    const float* x      = (const float*)d_in[0];
    const int*   ei     = (const int*)d_in[1];
    const float* w_gcn  = (const float*)d_in[2];
    const float* b_gcn  = (const float*)d_in[3];
    const float* wq     = (const float*)d_in[4];
    const float* bq     = (const float*)d_in[5];
    const float* wk     = (const float*)d_in[6];
    const float* bk     = (const float*)d_in[7];   // cancels in softmax
    const float* wv     = (const float*)d_in[8];
    const float* bv     = (const float*)d_in[9];
    const float* w_skip = (const float*)d_in[10];
    const float* b_skip = (const float*)d_in[11];
    const float* w_beta = (const float*)d_in[12];
    const float* g1     = (const float*)d_in[13];
    const float* b1     = (const float*)d_in[14];
    const float* g2     = (const float*)d_in[15];
    const float* b2     = (const float*)d_in[16];
    const float* w_rel  = (const float*)d_in[17];
    const float* w_root = (const float*)d_in[18];
    const float* lw     = (const float*)d_in[19];
    const float* gw     = (const float*)d_in[20];
    (void)bk;

    const int N = in_sizes[0] / D;
    const int E = in_sizes[1] / 2;
    const int* src = ei;
    const int* dst = ei + E;

    char* wsb = (char*)d_ws;
    size_t off = 0;
    auto alloc = [&](size_t bytes) -> void* {
        void* p = wsb + off;
        off += (bytes + 255) & ~(size_t)255;
        return p;
    };
    ushort_t* qtb      = (ushort_t*)alloc((size_t)N * 512 * 2);
    ushort_t* xbf      = (ushort_t*)alloc((size_t)N * 128 * 2);
    ushort_t* xr_bf    = (ushort_t*)alloc((size_t)N * 128 * 2);
    ushort_t* agg      = (ushort_t*)alloc((size_t)N * 640 * 2);
    float*    flagb    = (float*)alloc((size_t)N * 4);
    ushort_t* hln_bf   = (ushort_t*)alloc((size_t)N * 128 * 2);
    ushort_t* wt_all   = (ushort_t*)alloc(640 * 128 * 2);
    ushort_t* wt_vg    = (ushort_t*)alloc(256 * 128 * 2);
    ushort_t* wt_rel   = (ushort_t*)alloc(256 * 128 * 2);
    ushort_t* wt_root  = (ushort_t*)alloc(128 * 256 * 2);
    float*    bias_all = (float*)alloc(640 * 4);
    int*      deg      = (int*)alloc((size_t)N * 4);
    int*      row_start= (int*)alloc((size_t)(N + 1) * 4);
    int*      cursor   = (int*)alloc((size_t)N * 4);
    int*      csr_src  = (int*)alloc((size_t)E * 4);
    float*    dinv     = (float*)alloc((size_t)N * 4);
    int*      bsum     = (int*)alloc(((size_t)(N + 1023) / 1024) * 4);

    float* out = (float*)d_out;
    const int SB = (N + 1023) / 1024;

    // ---- graph prep ----
    hipMemsetAsync(deg, 0, (size_t)N * sizeof(int), stream);
    deg_count_kernel<<<dim3((E + 255) / 256), dim3(256), 0, stream>>>(dst, deg, E);
    scan1_kernel<<<dim3(SB), dim3(256), 0, stream>>>(deg, row_start, bsum, N);
    scan2_kernel<<<dim3(1), dim3(256), 0, stream>>>(bsum, SB);
    scan3_kernel<<<dim3((N + 255) / 256), dim3(256), 0, stream>>>(
        deg, bsum, row_start, cursor, dinv, N, E);
    fill_kernel<<<dim3((E + 255) / 256), dim3(256), 0, stream>>>(src, dst, cursor, csr_src, E);

    // ---- weights (incl. Wq@Wk^T fold) ----
    const int PW = (640 * 128 + 640 + 2 * 256 * 128 + 128 * 256 + 255) / 256;
    pack_weights_kernel<<<dim3(PW), dim3(256), 0, stream>>>(
        w_gcn, wq, wk, wv, w_skip, bq, b_skip, w_rel, w_root,
        wt_all, wt_vg, wt_rel, wt_root, bias_all);

    // ---- projections: qt | xr (+ xbf emit) ----
    const int MB = (N + 127) / 128;
    proj_gemm<<<dim3(MB, 2), dim3(256), 0, stream>>>(
        x, wt_all, bias_all, qtb, xr_bf, xbf, N);

    // ---- edge phase: gathers x only ----
    edge_fused_kernel<<<dim3((N + 3) / 4), dim3(256), 0, stream>>>(
        xbf, qtb, row_start, csr_src, dinv, agg, flagb, N);

    // ---- combine + beta + LN1 ----
    combine_ln1<<<dim3(MB), dim3(256), 0, stream>>>(
        agg, wt_vg, bv, b_gcn, flagb, xr_bf, w_beta, g1, b1, lw, gw, hln_bf, N);

    // ---- fused FFN + LN2 ----
    ffn_fused<<<dim3(MB), dim3(256), 0, stream>>>(
        hln_bf, wt_rel, wt_root, g2, b2, out, N);
}

// Round 7
// 241.455 us; speedup vs baseline: 1.4158x; 1.4158x over previous
//
#include <hip/hip_runtime.h>
#include <math.h>

#define D 128
#define EPSV 1e-5f

typedef unsigned short ushort_t;
typedef __attribute__((ext_vector_type(8))) short short8v;
typedef __attribute__((ext_vector_type(4))) float f32x4;

__device__ __forceinline__ float bf2f(unsigned u) {
    return __uint_as_float(u << 16);
}
__device__ __forceinline__ ushort_t f2bf(float f) {
    unsigned u = __float_as_uint(f);
    unsigned r = (u + 0x7fffu + ((u >> 16) & 1u)) >> 16;   // RNE
    return (ushort_t)r;
}
__device__ __forceinline__ float bfp(uint4 v, int i) {   // bf16 element i of 8
    unsigned w = (&v.x)[i >> 1];
    return bf2f((i & 1) ? (w >> 16) : (w & 0xffffu));
}

// ============ projection GEMM: pack/q/xr = x @ [w_gcn|wq|wk|wv|w_skip] ============
// grid (MB, 2): blockIdx.y splits col-tiles {0,1,2} / {3,4} for 2x parallelism.
// A fragments loaded once (f32 -> bf16), B direct from global (L2-hot).
__global__ __launch_bounds__(256)
void proj_gemm(const float* __restrict__ x,
               const ushort_t* __restrict__ Bt,   // wt_all [640][128]
               const float* __restrict__ bias,    // [640]
               ushort_t* __restrict__ pack, ushort_t* __restrict__ qb,
               ushort_t* __restrict__ xrb, int M)
{
    __shared__ ushort_t Cs[128 * 136];
    const int tid = threadIdx.x, lane = tid & 63, wid = tid >> 6;
    const int wr = wid >> 1, wc = wid & 1;
    const int R0 = blockIdx.x * 128;
    const int cbeg = blockIdx.y ? 3 : 0;
    const int cend = blockIdx.y ? 5 : 3;

    short8v av[4][4];                         // [r][ks], bf16 converted from f32 x
    #pragma unroll
    for (int r = 0; r < 4; ++r) {
        int gr = R0 + wr * 64 + r * 16 + (lane & 15);
        if (gr >= M) gr = M - 1;
        const float* xrow = x + (size_t)gr * 128 + (lane >> 4) * 8;
        #pragma unroll
        for (int ks = 0; ks < 4; ++ks) {
            float4 lo = *reinterpret_cast<const float4*>(xrow + ks * 32);
            float4 hi = *reinterpret_cast<const float4*>(xrow + ks * 32 + 4);
            short8v a;
            a[0] = (short)f2bf(lo.x); a[1] = (short)f2bf(lo.y);
            a[2] = (short)f2bf(lo.z); a[3] = (short)f2bf(lo.w);
            a[4] = (short)f2bf(hi.x); a[5] = (short)f2bf(hi.y);
            a[6] = (short)f2bf(hi.z); a[7] = (short)f2bf(hi.w);
            av[r][ks] = a;
        }
    }

    for (int ct = cbeg; ct < cend; ++ct) {
        f32x4 acc[4][4] = {};
        #pragma unroll
        for (int ks = 0; ks < 4; ++ks) {
            short8v bv[4];
            #pragma unroll
            for (int c = 0; c < 4; ++c) {
                int col = ct * 128 + wc * 64 + c * 16 + (lane & 15);
                bv[c] = *reinterpret_cast<const short8v*>(
                    &Bt[(size_t)col * 128 + ks * 32 + (lane >> 4) * 8]);
            }
            #pragma unroll
            for (int r = 0; r < 4; ++r)
                #pragma unroll
                for (int c = 0; c < 4; ++c)
                    acc[r][c] = __builtin_amdgcn_mfma_f32_16x16x32_bf16(av[r][ks], bv[c], acc[r][c], 0, 0, 0);
        }
        __syncthreads();                      // Cs free from previous ct
        #pragma unroll
        for (int r = 0; r < 4; ++r) {
            int rowb = wr * 64 + r * 16 + (lane >> 4) * 4;
            #pragma unroll
            for (int i = 0; i < 4; ++i)
                #pragma unroll
                for (int c = 0; c < 4; ++c) {
                    int col = wc * 64 + c * 16 + (lane & 15);
                    Cs[(rowb + i) * 136 + col] = f2bf(acc[r][c][i] + bias[ct * 128 + col]);
                }
        }
        __syncthreads();
        #pragma unroll
        for (int it = 0; it < 8; ++it) {      // 128 rows x 16 chunks of 16B
            int linear = tid + it * 256;
            int row = linear >> 4, ch = linear & 15;
            int gr = R0 + row;
            if (gr < M) {
                uint4 v = *reinterpret_cast<const uint4*>(&Cs[row * 136 + ch * 8]);
                ushort_t* dst;
                if (ct == 0)      dst = pack + (size_t)gr * 384 + 256;  // xw
                else if (ct == 1) dst = qb   + (size_t)gr * 128;        // q
                else if (ct == 2) dst = pack + (size_t)gr * 384;        // k
                else if (ct == 3) dst = pack + (size_t)gr * 384 + 128;  // v
                else              dst = xrb  + (size_t)gr * 128;        // x_r
                *reinterpret_cast<uint4*>(dst + ch * 8) = v;
            }
        }
    }
}

// ============ fused FFN1 + FFN2 + residual + LayerNorm2 -> f32 out ============
// BM=64: hidden [64][256] bf16 in LDS (swizzled), 33.3 KB total -> 4 blocks/CU.
__device__ __forceinline__ int swz(int ch, int row) {
    return (ch & 24) | ((ch ^ row) & 7);
}

__global__ __launch_bounds__(256)
void ffn_fused(const ushort_t* __restrict__ hlnb,     // [M][128] bf16
               const ushort_t* __restrict__ wt_rel,   // [256][128] bf16
               const ushort_t* __restrict__ wt_root,  // [128][256] bf16
               const float* __restrict__ g2, const float* __restrict__ b2,
               float* __restrict__ outf, int M)
{
    __shared__ float smem[64 * 130];                  // 33.3 KB
    ushort_t* Hs = (ushort_t*)smem;                   // hidden bf16 [64][256] swizzled
    const int tid = threadIdx.x, lane = tid & 63, wid = tid >> 6;
    const int wr = wid >> 1, wc = wid & 1;
    const int R0 = blockIdx.x * 64;

    // ---- FFN1: hidden = relu(hln @ w_rel) -> LDS ----
    short8v av[2][4];
    #pragma unroll
    for (int r = 0; r < 2; ++r) {
        int gr = R0 + wr * 32 + r * 16 + (lane & 15);
        if (gr >= M) gr = M - 1;
        #pragma unroll
        for (int ks = 0; ks < 4; ++ks)
            av[r][ks] = *reinterpret_cast<const short8v*>(
                &hlnb[(size_t)gr * 128 + ks * 32 + (lane >> 4) * 8]);
    }
    #pragma unroll
    for (int ct = 0; ct < 2; ++ct) {
        f32x4 acc[2][4] = {};
        #pragma unroll
        for (int ks = 0; ks < 4; ++ks) {
            short8v bv[4];
            #pragma unroll
            for (int c = 0; c < 4; ++c) {
                int col = ct * 128 + wc * 64 + c * 16 + (lane & 15);
                bv[c] = *reinterpret_cast<const short8v*>(
                    &wt_rel[(size_t)col * 128 + ks * 32 + (lane >> 4) * 8]);
            }
            #pragma unroll
            for (int r = 0; r < 2; ++r)
                #pragma unroll
                for (int c = 0; c < 4; ++c)
                    acc[r][c] = __builtin_amdgcn_mfma_f32_16x16x32_bf16(av[r][ks], bv[c], acc[r][c], 0, 0, 0);
        }
        #pragma unroll
        for (int r = 0; r < 2; ++r) {
            int rowb = wr * 32 + r * 16 + (lane >> 4) * 4;
            #pragma unroll
            for (int i = 0; i < 4; ++i)
                #pragma unroll
                for (int c = 0; c < 4; ++c) {
                    int row = rowb + i;
                    int col = ct * 128 + wc * 64 + c * 16 + (lane & 15);
                    int ch = col >> 3, el = col & 7;
                    Hs[row * 256 + swz(ch, row) * 8 + el] = f2bf(fmaxf(acc[r][c][i], 0.f));
                }
        }
    }
    __syncthreads();

    // ---- FFN2: acc2 = hidden @ w_root ----
    f32x4 acc2[2][4] = {};
    #pragma unroll
    for (int ks = 0; ks < 8; ++ks) {
        short8v a2[2], bv[4];
        #pragma unroll
        for (int r = 0; r < 2; ++r) {
            int row = wr * 32 + r * 16 + (lane & 15);
            int ch = ks * 4 + (lane >> 4);
            a2[r] = *reinterpret_cast<const short8v*>(&Hs[row * 256 + swz(ch, row) * 8]);
        }
        #pragma unroll
        for (int c = 0; c < 4; ++c) {
            int col = wc * 64 + c * 16 + (lane & 15);
            bv[c] = *reinterpret_cast<const short8v*>(
                &wt_root[(size_t)col * 256 + ks * 32 + (lane >> 4) * 8]);
        }
        #pragma unroll
        for (int r = 0; r < 2; ++r)
            #pragma unroll
            for (int c = 0; c < 4; ++c)
                acc2[r][c] = __builtin_amdgcn_mfma_f32_16x16x32_bf16(a2[r], bv[c], acc2[r][c], 0, 0, 0);
    }
    __syncthreads();                          // hidden reads done; reuse as f32 C

    float* Cs = smem;                         // [64][130]
    #pragma unroll
    for (int r = 0; r < 2; ++r) {
        int rowb = wr * 32 + r * 16 + (lane >> 4) * 4;
        #pragma unroll
        for (int i = 0; i < 4; ++i)
            #pragma unroll
            for (int c = 0; c < 4; ++c)
                Cs[(rowb + i) * 130 + wc * 64 + c * 16 + (lane & 15)] = acc2[r][c][i];
    }
    __syncthreads();

    const float ga = g2[lane * 2], gb = g2[lane * 2 + 1];
    const float ba = b2[lane * 2], bb2 = b2[lane * 2 + 1];
    for (int rr = 0; rr < 16; ++rr) {
        int row = wid * 16 + rr;
        int gr = R0 + row;
        if (gr >= M) break;
        unsigned hu = *reinterpret_cast<const unsigned*>(&hlnb[(size_t)gr * 128 + lane * 2]);
        float t0 = Cs[row * 130 + lane * 2]     + bf2f(hu & 0xffffu);
        float t1 = Cs[row * 130 + lane * 2 + 1] + bf2f(hu >> 16);
        float ssum = t0 + t1;
        #pragma unroll
        for (int off = 1; off <= 32; off <<= 1) ssum += __shfl_xor(ssum, off);
        float mu = ssum * (1.f / 128.f);
        float dv0 = t0 - mu, dv1 = t1 - mu;
        float vsum = dv0 * dv0 + dv1 * dv1;
        #pragma unroll
        for (int off = 1; off <= 32; off <<= 1) vsum += __shfl_xor(vsum, off);
        float rs = rsqrtf(vsum * (1.f / 128.f) + EPSV);
        float2 o = make_float2(dv0 * rs * ga + ba, dv1 * rs * gb + bb2);
        *reinterpret_cast<float2*>(&outf[(size_t)gr * 128 + lane * 2]) = o;
    }
}

// =================== weight packing ===================
__global__ void pack_weights_kernel(const float* __restrict__ wg, const float* __restrict__ wq,
                                    const float* __restrict__ wk, const float* __restrict__ wv,
                                    const float* __restrict__ wsk,
                                    const float* __restrict__ bq, const float* __restrict__ bk,
                                    const float* __restrict__ bv, const float* __restrict__ bsk,
                                    const float* __restrict__ wrel, const float* __restrict__ wroot,
                                    ushort_t* __restrict__ wt_all, ushort_t* __restrict__ wt_rel,
                                    ushort_t* __restrict__ wt_root, float* __restrict__ bias_all)
{
    int i = blockIdx.x * 256 + threadIdx.x;
    if (i < 640 * 128) {                         // wt_all[n][k] = W[k][n], 5 concat weights
        int n = i >> 7, k = i & 127;
        const float* srcs[5] = {wg, wq, wk, wv, wsk};
        wt_all[i] = f2bf(srcs[n >> 7][k * 128 + (n & 127)]);
    } else if (i < 640 * 128 + 256 * 128) {      // wt_rel[n][k] = w_rel[k][n]
        int j = i - 640 * 128;
        int n = j >> 7, k = j & 127;
        wt_rel[j] = f2bf(wrel[k * 256 + n]);
    } else if (i < 640 * 128 + 256 * 128 + 128 * 256) {  // wt_root[n][k] = w_root[k][n]
        int j = i - (640 * 128 + 256 * 128);
        int n = j >> 8, k = j & 255;
        wt_root[j] = f2bf(wroot[k * 128 + n]);
    } else if (i < 640 * 128 + 256 * 128 + 128 * 256 + 640) {
        int n = i - (640 * 128 + 256 * 128 + 128 * 256);
        float b = 0.f;                           // cols [0,128) = gcn: bias added in edge kernel
        if (n >= 128) {
            const float* bs[4] = {bq, bk, bv, bsk};
            b = bs[(n - 128) >> 7][n & 127];
        }
        bias_all[n] = b;
    }
}

// =================== graph prep ===================
__global__ void deg_count_kernel(const int* __restrict__ dst, int* __restrict__ deg, int E)
{
    int e = blockIdx.x * blockDim.x + threadIdx.x;
    if (e < E) atomicAdd(&deg[dst[e]], 1);
}

// block-local exclusive scan over chunks of 1024 (256 thr x 4), emits block sums
__global__ __launch_bounds__(256)
void scan1_kernel(const int* __restrict__ deg, int* __restrict__ row_start,
                  int* __restrict__ bsum, int n)
{
    __shared__ int ws[4];
    const int t = threadIdx.x, lane = t & 63, wid = t >> 6;
    const int base = blockIdx.x * 1024 + t * 4;
    int v0 = 0, v1 = 0, v2 = 0, v3 = 0;
    if (base + 3 < n) {
        int4 q = *reinterpret_cast<const int4*>(&deg[base]);
        v0 = q.x; v1 = q.y; v2 = q.z; v3 = q.w;
    } else {
        if (base < n)     v0 = deg[base];
        if (base + 1 < n) v1 = deg[base + 1];
        if (base + 2 < n) v2 = deg[base + 2];
        if (base + 3 < n) v3 = deg[base + 3];
    }
    int tot = v0 + v1 + v2 + v3;
    int inc = tot;
    #pragma unroll
    for (int off = 1; off < 64; off <<= 1) {
        int y = __shfl_up(inc, off);
        if (lane >= off) inc += y;
    }
    if (lane == 63) ws[wid] = inc;
    __syncthreads();
    int woff = 0;
    for (int w = 0; w < wid; ++w) woff += ws[w];
    int excl = woff + inc - tot;
    if (base < n)     row_start[base]     = excl;
    if (base + 1 < n) row_start[base + 1] = excl + v0;
    if (base + 2 < n) row_start[base + 2] = excl + v0 + v1;
    if (base + 3 < n) row_start[base + 3] = excl + v0 + v1 + v2;
    if (t == 0) bsum[blockIdx.x] = ws[0] + ws[1] + ws[2] + ws[3];
}

// apply block offsets (prefix computed in-block: SB small); derive cursor, dinv, row_start[n]
__global__ __launch_bounds__(256)
void scan3_kernel(const int* __restrict__ deg, const int* __restrict__ bsum,
                  int* __restrict__ row_start, int* __restrict__ cursor,
                  float* __restrict__ dinv, int n, int E)
{
    __shared__ int boff_s;
    const int K = blockIdx.x >> 2;          // 256-thread block spans 1/4 of a 1024-chunk
    if (threadIdx.x == 0) {
        int s = 0;
        for (int j = 0; j < K; ++j) s += bsum[j];
        boff_s = s;
    }
    __syncthreads();
    int i = blockIdx.x * 256 + threadIdx.x;
    if (i < n) {
        int rs = row_start[i] + boff_s;
        row_start[i] = rs;
        cursor[i] = rs;
        int d = deg[i];
        dinv[i] = (d > 0) ? rsqrtf((float)d) : 0.f;
    }
    if (i == 0) row_start[n] = E;
}

__global__ void fill_kernel(const int* __restrict__ src, const int* __restrict__ dst,
                            int* __restrict__ cursor, int* __restrict__ csr_src, int E)
{
    int e = blockIdx.x * blockDim.x + threadIdx.x;
    if (e < E) {
        int d = dst[e];
        int pos = atomicAdd(&cursor[d], 1);
        csr_src[pos] = src[e];
    }
}

// ===== fused: GCN gather + attention + beta gate + combine + LayerNorm1 =====
// pack: [N][384] bf16 = k(128) | v(128) | xw(128). 4 edges in parallel per wave:
// slot = lane>>4 (edge), li = lane&15 (8 dims each). No online max (|alpha| << 1).
__global__ __launch_bounds__(256)
void edge_fused_kernel(const ushort_t* __restrict__ pack,
                       const ushort_t* __restrict__ qbf,
                       const ushort_t* __restrict__ xrbf,
                       const int* __restrict__ row_start,
                       const int* __restrict__ csr_src,
                       const float* __restrict__ dinv,
                       const float* __restrict__ b_gcn,
                       const float* __restrict__ w_beta,
                       const float* __restrict__ g1, const float* __restrict__ b1,
                       const float* __restrict__ local_w, const float* __restrict__ global_w,
                       ushort_t* __restrict__ hln_bf, int n)
{
    const int wid = threadIdx.x >> 6, lane = threadIdx.x & 63;
    const int node = blockIdx.x * 4 + wid;
    if (node >= n) return;
    const int slot = lane >> 4, li = lane & 15;
    const int d8 = li * 8;

    uint4 qu = *reinterpret_cast<const uint4*>(&qbf[(size_t)node * 128 + d8]);
    float q[8];
    #pragma unroll
    for (int i = 0; i < 8; ++i) q[i] = bfp(qu, i);

    const int e0 = row_start[node], e1 = row_start[node + 1];
    const float dn = dinv[node];
    const float scale = 0.17677669529663687f;  // 1/sqrt(32)

    float s = 0.f, va[8] = {}, ga[8] = {};

    for (int j = e0; j < e1; j += 4) {
        const int je = j + slot;
        const bool act = je < e1;
        const int sidx = act ? csr_src[je] : 0;
        const ushort_t* prow = pack + (size_t)sidx * 384;
        uint4 ku = *reinterpret_cast<const uint4*>(&prow[d8]);
        uint4 vu = *reinterpret_cast<const uint4*>(&prow[128 + d8]);
        uint4 xu = *reinterpret_cast<const uint4*>(&prow[256 + d8]);
        float p = 0.f;
        #pragma unroll
        for (int i = 0; i < 8; ++i) p = fmaf(q[i], bfp(ku, i), p);
        p += __shfl_xor(p, 1);                   // head = li>>2 : 4-lane groups
        p += __shfl_xor(p, 2);
        float wgt = act ? __expf(p * scale) : 0.f;
        float c   = act ? dn * dinv[sidx] : 0.f;
        s += wgt;
        #pragma unroll
        for (int i = 0; i < 8; ++i) {
            va[i] = fmaf(wgt, bfp(vu, i), va[i]);
            ga[i] = fmaf(c,   bfp(xu, i), ga[i]);
        }
    }
    // combine the 4 slots (butterfly over lane bits 4,5)
    #pragma unroll
    for (int off = 16; off <= 32; off <<= 1) {
        s += __shfl_xor(s, off);
        #pragma unroll
        for (int i = 0; i < 8; ++i) {
            va[i] += __shfl_xor(va[i], off);
            ga[i] += __shfl_xor(ga[i], off);
        }
    }
    const float denom = fmaxf(s, 1e-16f);        // per-head (head = li>>2)

    uint4 xru = *reinterpret_cast<const uint4*>(&xrbf[(size_t)node * 128 + d8]);
    float t[8];
    float part = 0.f;
    #pragma unroll
    for (int i = 0; i < 8; ++i) {
        float og = va[i] / denom;
        float xr = bfp(xru, i);
        float lo = ga[i] + b_gcn[d8 + i];
        part += og * w_beta[d8 + i] + xr * w_beta[128 + d8 + i]
              + (og - xr) * w_beta[256 + d8 + i];
        t[i] = lo;
        va[i] = og; ga[i] = xr;                   // reuse regs: va=og, ga=xr
    }
    #pragma unroll
    for (int off = 1; off <= 32; off <<= 1) part += __shfl_xor(part, off);
    const float beta = 1.f / (1.f + __expf(-part * 0.25f));   // 4x duplication

    const float lw = local_w[0], gw = global_w[0];
    float ssum = 0.f;
    #pragma unroll
    for (int i = 0; i < 8; ++i) {
        float go = beta * ga[i] + (1.f - beta) * va[i];
        t[i] = 2.f * (lw * t[i] + gw * go);
        ssum += t[i];
    }
    #pragma unroll
    for (int off = 1; off <= 32; off <<= 1) ssum += __shfl_xor(ssum, off);
    const float mu = ssum * (1.f / 512.f);        // 128 dims x4 duplication
    float vsum = 0.f;
    #pragma unroll
    for (int i = 0; i < 8; ++i) { float d = t[i] - mu; vsum += d * d; }
    #pragma unroll
    for (int off = 1; off <= 32; off <<= 1) vsum += __shfl_xor(vsum, off);
    const float rs = rsqrtf(vsum * (1.f / 512.f) + EPSV);

    if (slot == 0) {
        uint4 o;
        #pragma unroll
        for (int i = 0; i < 4; ++i) {
            float o0 = (t[2*i]   - mu) * rs * g1[d8 + 2*i]   + b1[d8 + 2*i];
            float o1 = (t[2*i+1] - mu) * rs * g1[d8 + 2*i+1] + b1[d8 + 2*i+1];
            (&o.x)[i] = (unsigned)f2bf(o0) | ((unsigned)f2bf(o1) << 16);
        }
        *reinterpret_cast<uint4*>(&hln_bf[(size_t)node * 128 + d8]) = o;
    }
}

// =================== launch ===================
extern "C" void kernel_launch(void* const* d_in, const int* in_sizes, int n_in,
                              void* d_out, int out_size, void* d_ws, size_t ws_size,
                              hipStream_t stream)
{
    const float* x      = (const float*)d_in[0];
    const int*   ei     = (const int*)d_in[1];
    const float* w_gcn  = (const float*)d_in[2];
    const float* b_gcn  = (const float*)d_in[3];
    const float* wq     = (const float*)d_in[4];
    const float* bq     = (const float*)d_in[5];
    const float* wk     = (const float*)d_in[6];
    const float* bk     = (const float*)d_in[7];
    const float* wv     = (const float*)d_in[8];
    const float* bv     = (const float*)d_in[9];
    const float* w_skip = (const float*)d_in[10];
    const float* b_skip = (const float*)d_in[11];
    const float* w_beta = (const float*)d_in[12];
    const float* g1     = (const float*)d_in[13];
    const float* b1     = (const float*)d_in[14];
    const float* g2     = (const float*)d_in[15];
    const float* b2     = (const float*)d_in[16];
    const float* w_rel  = (const float*)d_in[17];
    const float* w_root = (const float*)d_in[18];
    const float* lw     = (const float*)d_in[19];
    const float* gw     = (const float*)d_in[20];

    const int N = in_sizes[0] / D;
    const int E = in_sizes[1] / 2;
    const int* src = ei;
    const int* dst = ei + E;

    char* wsb = (char*)d_ws;
    size_t off = 0;
    auto alloc = [&](size_t bytes) -> void* {
        void* p = wsb + off;
        off += (bytes + 255) & ~(size_t)255;
        return p;
    };
    ushort_t* pack_kvx = (ushort_t*)alloc((size_t)N * 384 * 2);  // k|v|xw bf16
    ushort_t* qb_bf    = (ushort_t*)alloc((size_t)N * 128 * 2);
    ushort_t* xr_bf    = (ushort_t*)alloc((size_t)N * 128 * 2);
    ushort_t* hln_bf   = (ushort_t*)alloc((size_t)N * 128 * 2);
    ushort_t* wt_all   = (ushort_t*)alloc(640 * 128 * 2);
    ushort_t* wt_rel   = (ushort_t*)alloc(256 * 128 * 2);
    ushort_t* wt_root  = (ushort_t*)alloc(128 * 256 * 2);
    float*    bias_all = (float*)alloc(640 * 4);
    int*      deg      = (int*)alloc((size_t)N * 4);
    int*      row_start= (int*)alloc((size_t)(N + 1) * 4);
    int*      cursor   = (int*)alloc((size_t)N * 4);
    int*      csr_src  = (int*)alloc((size_t)E * 4);
    float*    dinv     = (float*)alloc((size_t)N * 4);
    int*      bsum     = (int*)alloc(((size_t)(N + 1023) / 1024) * 4);

    float* out = (float*)d_out;
    const int SB = (N + 1023) / 1024;

    // ---- graph prep ----
    hipMemsetAsync(deg, 0, (size_t)N * sizeof(int), stream);
    deg_count_kernel<<<dim3((E + 255) / 256), dim3(256), 0, stream>>>(dst, deg, E);
    scan1_kernel<<<dim3(SB), dim3(256), 0, stream>>>(deg, row_start, bsum, N);
    scan3_kernel<<<dim3((N + 255) / 256), dim3(256), 0, stream>>>(
        deg, bsum, row_start, cursor, dinv, N, E);
    fill_kernel<<<dim3((E + 255) / 256), dim3(256), 0, stream>>>(src, dst, cursor, csr_src, E);

    // ---- weights ----
    pack_weights_kernel<<<dim3(579), dim3(256), 0, stream>>>(
        w_gcn, wq, wk, wv, w_skip, bq, bk, bv, b_skip, w_rel, w_root,
        wt_all, wt_rel, wt_root, bias_all);

    // ---- fused projections (reads f32 x directly) ----
    const int MB = (N + 127) / 128;
    proj_gemm<<<dim3(MB, 2), dim3(256), 0, stream>>>(
        x, wt_all, bias_all, pack_kvx, qb_bf, xr_bf, N);

    // ---- fused edge phase ----
    edge_fused_kernel<<<dim3((N + 3) / 4), dim3(256), 0, stream>>>(
        pack_kvx, qb_bf, xr_bf, row_start, csr_src, dinv, b_gcn, w_beta,
        g1, b1, lw, gw, hln_bf, N);

    // ---- fused FFN + LN2 (BM=64, 4 blocks/CU) ----
    const int MB2 = (N + 63) / 64;
    ffn_fused<<<dim3(MB2), dim3(256), 0, stream>>>(
        hln_bf, wt_rel, wt_root, g2, b2, out, N);
}

// Round 8
// 215.143 us; speedup vs baseline: 1.5890x; 1.1223x over previous
//
#include <hip/hip_runtime.h>
#include <math.h>

#define D 128
#define EPSV 1e-5f

typedef unsigned short ushort_t;
typedef unsigned char uchar_t;
typedef __attribute__((ext_vector_type(8))) short short8v;
typedef __attribute__((ext_vector_type(4))) float f32x4;
typedef __attribute__((ext_vector_type(2))) float f32x2;

__device__ __forceinline__ float bf2f(unsigned u) {
    return __uint_as_float(u << 16);
}
__device__ __forceinline__ ushort_t f2bf(float f) {
    unsigned u = __float_as_uint(f);
    unsigned r = (u + 0x7fffu + ((u >> 16) & 1u)) >> 16;   // RNE
    return (ushort_t)r;
}
__device__ __forceinline__ float bfp(uint4 v, int i) {   // bf16 element i of 8
    unsigned w = (&v.x)[i >> 1];
    return bf2f((i & 1) ? (w >> 16) : (w & 0xffffu));
}

// unpack 8 fp8 (e4m3, 8 bytes in uint2) -> 8 f32 via HW cvt (4 ops)
#define UNPACK8_FP8(u, o) { \
    f32x2 _a = __builtin_amdgcn_cvt_pk_f32_fp8((int)(u).x, false); \
    f32x2 _b = __builtin_amdgcn_cvt_pk_f32_fp8((int)(u).x, true);  \
    f32x2 _c = __builtin_amdgcn_cvt_pk_f32_fp8((int)(u).y, false); \
    f32x2 _d = __builtin_amdgcn_cvt_pk_f32_fp8((int)(u).y, true);  \
    o[0] = _a.x; o[1] = _a.y; o[2] = _b.x; o[3] = _b.y;            \
    o[4] = _c.x; o[5] = _c.y; o[6] = _d.x; o[7] = _d.y; }

// pack 4 bf16 (in uints w0=[e1|e0], w1=[e3|e2]) -> 4 fp8 in one uint
__device__ __forceinline__ unsigned bf4_to_fp8x4(unsigned w0, unsigned w1) {
    int u = __builtin_amdgcn_cvt_pk_fp8_f32(bf2f(w0 & 0xffffu), bf2f(w0 >> 16), 0, false);
    u = __builtin_amdgcn_cvt_pk_fp8_f32(bf2f(w1 & 0xffffu), bf2f(w1 >> 16), u, true);
    return (unsigned)u;
}

// ============ projection GEMM: pack/q/xr = x @ [w_gcn|wq|wk|wv|w_skip] ============
// pack: [N][384] BYTES fp8 = k(128) | v(128) | xw(128). q, xr stay bf16.
// grid (MB, 2): blockIdx.y splits col-tiles {0,1,2} / {3,4}.
__global__ __launch_bounds__(256)
void proj_gemm(const float* __restrict__ x,
               const ushort_t* __restrict__ Bt,   // wt_all [640][128]
               const float* __restrict__ bias,    // [640]
               uchar_t* __restrict__ pack, ushort_t* __restrict__ qb,
               ushort_t* __restrict__ xrb, int M)
{
    __shared__ ushort_t Cs[128 * 136];
    const int tid = threadIdx.x, lane = tid & 63, wid = tid >> 6;
    const int wr = wid >> 1, wc = wid & 1;
    const int R0 = blockIdx.x * 128;
    const int cbeg = blockIdx.y ? 3 : 0;
    const int cend = blockIdx.y ? 5 : 3;

    short8v av[4][4];                         // [r][ks], bf16 converted from f32 x
    #pragma unroll
    for (int r = 0; r < 4; ++r) {
        int gr = R0 + wr * 64 + r * 16 + (lane & 15);
        if (gr >= M) gr = M - 1;
        const float* xrow = x + (size_t)gr * 128 + (lane >> 4) * 8;
        #pragma unroll
        for (int ks = 0; ks < 4; ++ks) {
            float4 lo = *reinterpret_cast<const float4*>(xrow + ks * 32);
            float4 hi = *reinterpret_cast<const float4*>(xrow + ks * 32 + 4);
            short8v a;
            a[0] = (short)f2bf(lo.x); a[1] = (short)f2bf(lo.y);
            a[2] = (short)f2bf(lo.z); a[3] = (short)f2bf(lo.w);
            a[4] = (short)f2bf(hi.x); a[5] = (short)f2bf(hi.y);
            a[6] = (short)f2bf(hi.z); a[7] = (short)f2bf(hi.w);
            av[r][ks] = a;
        }
    }

    for (int ct = cbeg; ct < cend; ++ct) {
        f32x4 acc[4][4] = {};
        #pragma unroll
        for (int ks = 0; ks < 4; ++ks) {
            short8v bv[4];
            #pragma unroll
            for (int c = 0; c < 4; ++c) {
                int col = ct * 128 + wc * 64 + c * 16 + (lane & 15);
                bv[c] = *reinterpret_cast<const short8v*>(
                    &Bt[(size_t)col * 128 + ks * 32 + (lane >> 4) * 8]);
            }
            #pragma unroll
            for (int r = 0; r < 4; ++r)
                #pragma unroll
                for (int c = 0; c < 4; ++c)
                    acc[r][c] = __builtin_amdgcn_mfma_f32_16x16x32_bf16(av[r][ks], bv[c], acc[r][c], 0, 0, 0);
        }
        __syncthreads();                      // Cs free from previous ct
        #pragma unroll
        for (int r = 0; r < 4; ++r) {
            int rowb = wr * 64 + r * 16 + (lane >> 4) * 4;
            #pragma unroll
            for (int i = 0; i < 4; ++i)
                #pragma unroll
                for (int c = 0; c < 4; ++c) {
                    int col = wc * 64 + c * 16 + (lane & 15);
                    Cs[(rowb + i) * 136 + col] = f2bf(acc[r][c][i] + bias[ct * 128 + col]);
                }
        }
        __syncthreads();
        if (ct == 1 || ct == 4) {             // bf16 outputs: q, x_r
            #pragma unroll
            for (int it = 0; it < 8; ++it) {  // 128 rows x 16 chunks of 16B
                int linear = tid + it * 256;
                int row = linear >> 4, ch = linear & 15;
                int gr = R0 + row;
                if (gr < M) {
                    uint4 v = *reinterpret_cast<const uint4*>(&Cs[row * 136 + ch * 8]);
                    ushort_t* dst = (ct == 1) ? (qb + (size_t)gr * 128)
                                              : (xrb + (size_t)gr * 128);
                    *reinterpret_cast<uint4*>(dst + ch * 8) = v;
                }
            }
        } else {                              // fp8 outputs: xw(ct0), k(ct2), v(ct3)
            const int byteoff = (ct == 0) ? 256 : (ct == 2) ? 0 : 128;
            #pragma unroll
            for (int it = 0; it < 4; ++it) {  // 128 rows x 8 chunks of 16 fp8
                int linear = tid + it * 256;
                int row = linear >> 3, ch = linear & 7;
                int gr = R0 + row;
                if (gr < M) {
                    uint4 lo = *reinterpret_cast<const uint4*>(&Cs[row * 136 + ch * 16]);
                    uint4 hi = *reinterpret_cast<const uint4*>(&Cs[row * 136 + ch * 16 + 8]);
                    uint4 o;
                    o.x = bf4_to_fp8x4(lo.x, lo.y);
                    o.y = bf4_to_fp8x4(lo.z, lo.w);
                    o.z = bf4_to_fp8x4(hi.x, hi.y);
                    o.w = bf4_to_fp8x4(hi.z, hi.w);
                    *reinterpret_cast<uint4*>(pack + (size_t)gr * 384 + byteoff + ch * 16) = o;
                }
            }
        }
    }
}

// ============ fused FFN1 + FFN2 + residual + LayerNorm2 -> f32 out ============
// hidden [128][256] bf16 lives only in LDS (swizzled); f32 C buffer aliases it.
__device__ __forceinline__ int swz(int ch, int row) {
    return (ch & 24) | ((ch ^ row) & 7);
}

__global__ __launch_bounds__(256)
void ffn_fused(const ushort_t* __restrict__ hlnb,     // [M][128] bf16
               const ushort_t* __restrict__ wt_rel,   // [256][128] bf16
               const ushort_t* __restrict__ wt_root,  // [128][256] bf16
               const float* __restrict__ g2, const float* __restrict__ b2,
               float* __restrict__ outf, int M)
{
    __shared__ float smem[128 * 130];                 // 66.6 KB
    ushort_t* Hs = (ushort_t*)smem;                   // hidden bf16 [128][256] swizzled
    const int tid = threadIdx.x, lane = tid & 63, wid = tid >> 6;
    const int wr = wid >> 1, wc = wid & 1;
    const int R0 = blockIdx.x * 128;

    short8v av[4][4];
    #pragma unroll
    for (int r = 0; r < 4; ++r) {
        int gr = R0 + wr * 64 + r * 16 + (lane & 15);
        if (gr >= M) gr = M - 1;
        #pragma unroll
        for (int ks = 0; ks < 4; ++ks)
            av[r][ks] = *reinterpret_cast<const short8v*>(
                &hlnb[(size_t)gr * 128 + ks * 32 + (lane >> 4) * 8]);
    }
    for (int ct = 0; ct < 2; ++ct) {
        f32x4 acc[4][4] = {};
        #pragma unroll
        for (int ks = 0; ks < 4; ++ks) {
            short8v bv[4];
            #pragma unroll
            for (int c = 0; c < 4; ++c) {
                int col = ct * 128 + wc * 64 + c * 16 + (lane & 15);
                bv[c] = *reinterpret_cast<const short8v*>(
                    &wt_rel[(size_t)col * 128 + ks * 32 + (lane >> 4) * 8]);
            }
            #pragma unroll
            for (int r = 0; r < 4; ++r)
                #pragma unroll
                for (int c = 0; c < 4; ++c)
                    acc[r][c] = __builtin_amdgcn_mfma_f32_16x16x32_bf16(av[r][ks], bv[c], acc[r][c], 0, 0, 0);
        }
        #pragma unroll
        for (int r = 0; r < 4; ++r) {
            int rowb = wr * 64 + r * 16 + (lane >> 4) * 4;
            #pragma unroll
            for (int i = 0; i < 4; ++i)
                #pragma unroll
                for (int c = 0; c < 4; ++c) {
                    int row = rowb + i;
                    int col = ct * 128 + wc * 64 + c * 16 + (lane & 15);
                    int ch = col >> 3, el = col & 7;
                    Hs[row * 256 + swz(ch, row) * 8 + el] = f2bf(fmaxf(acc[r][c][i], 0.f));
                }
        }
    }
    __syncthreads();

    f32x4 acc2[4][4] = {};
    #pragma unroll
    for (int ks = 0; ks < 8; ++ks) {
        short8v a2[4], bv[4];
        #pragma unroll
        for (int r = 0; r < 4; ++r) {
            int row = wr * 64 + r * 16 + (lane & 15);
            int ch = ks * 4 + (lane >> 4);
            a2[r] = *reinterpret_cast<const short8v*>(&Hs[row * 256 + swz(ch, row) * 8]);
        }
        #pragma unroll
        for (int c = 0; c < 4; ++c) {
            int col = wc * 64 + c * 16 + (lane & 15);
            bv[c] = *reinterpret_cast<const short8v*>(
                &wt_root[(size_t)col * 256 + ks * 32 + (lane >> 4) * 8]);
        }
        #pragma unroll
        for (int r = 0; r < 4; ++r)
            #pragma unroll
            for (int c = 0; c < 4; ++c)
                acc2[r][c] = __builtin_amdgcn_mfma_f32_16x16x32_bf16(a2[r], bv[c], acc2[r][c], 0, 0, 0);
    }
    __syncthreads();                          // hidden reads done; reuse as f32 C

    float* Cs = smem;                         // [128][130]
    #pragma unroll
    for (int r = 0; r < 4; ++r) {
        int rowb = wr * 64 + r * 16 + (lane >> 4) * 4;
        #pragma unroll
        for (int i = 0; i < 4; ++i)
            #pragma unroll
            for (int c = 0; c < 4; ++c)
                Cs[(rowb + i) * 130 + wc * 64 + c * 16 + (lane & 15)] = acc2[r][c][i];
    }
    __syncthreads();

    const float ga = g2[lane * 2], gb = g2[lane * 2 + 1];
    const float ba = b2[lane * 2], bb2 = b2[lane * 2 + 1];
    for (int rr = 0; rr < 32; ++rr) {
        int row = wid * 32 + rr;
        int gr = R0 + row;
        if (gr >= M) break;
        unsigned hu = *reinterpret_cast<const unsigned*>(&hlnb[(size_t)gr * 128 + lane * 2]);
        float t0 = Cs[row * 130 + lane * 2]     + bf2f(hu & 0xffffu);
        float t1 = Cs[row * 130 + lane * 2 + 1] + bf2f(hu >> 16);
        float ssum = t0 + t1;
        #pragma unroll
        for (int off = 1; off <= 32; off <<= 1) ssum += __shfl_xor(ssum, off);
        float mu = ssum * (1.f / 128.f);
        float dv0 = t0 - mu, dv1 = t1 - mu;
        float vsum = dv0 * dv0 + dv1 * dv1;
        #pragma unroll
        for (int off = 1; off <= 32; off <<= 1) vsum += __shfl_xor(vsum, off);
        float rs = rsqrtf(vsum * (1.f / 128.f) + EPSV);
        float2 o = make_float2(dv0 * rs * ga + ba, dv1 * rs * gb + bb2);
        *reinterpret_cast<float2*>(&outf[(size_t)gr * 128 + lane * 2]) = o;
    }
}

// =================== weight packing ===================
__global__ void pack_weights_kernel(const float* __restrict__ wg, const float* __restrict__ wq,
                                    const float* __restrict__ wk, const float* __restrict__ wv,
                                    const float* __restrict__ wsk,
                                    const float* __restrict__ bq, const float* __restrict__ bk,
                                    const float* __restrict__ bv, const float* __restrict__ bsk,
                                    const float* __restrict__ wrel, const float* __restrict__ wroot,
                                    ushort_t* __restrict__ wt_all, ushort_t* __restrict__ wt_rel,
                                    ushort_t* __restrict__ wt_root, float* __restrict__ bias_all)
{
    int i = blockIdx.x * 256 + threadIdx.x;
    if (i < 640 * 128) {                         // wt_all[n][k] = W[k][n], 5 concat weights
        int n = i >> 7, k = i & 127;
        const float* srcs[5] = {wg, wq, wk, wv, wsk};
        wt_all[i] = f2bf(srcs[n >> 7][k * 128 + (n & 127)]);
    } else if (i < 640 * 128 + 256 * 128) {      // wt_rel[n][k] = w_rel[k][n]
        int j = i - 640 * 128;
        int n = j >> 7, k = j & 127;
        wt_rel[j] = f2bf(wrel[k * 256 + n]);
    } else if (i < 640 * 128 + 256 * 128 + 128 * 256) {  // wt_root[n][k] = w_root[k][n]
        int j = i - (640 * 128 + 256 * 128);
        int n = j >> 8, k = j & 255;
        wt_root[j] = f2bf(wroot[k * 128 + n]);
    } else if (i < 640 * 128 + 256 * 128 + 128 * 256 + 640) {
        int n = i - (640 * 128 + 256 * 128 + 128 * 256);
        float b = 0.f;                           // cols [0,128) = gcn: bias added in edge kernel
        if (n >= 128) {
            const float* bs[4] = {bq, bk, bv, bsk};
            b = bs[(n - 128) >> 7][n & 127];
        }
        bias_all[n] = b;
    }
}

// =================== graph prep ===================
__global__ void deg_count_kernel(const int* __restrict__ dst, int* __restrict__ deg, int E)
{
    int e = blockIdx.x * blockDim.x + threadIdx.x;
    if (e < E) atomicAdd(&deg[dst[e]], 1);
}

// block-local exclusive scan over chunks of 1024 (256 thr x 4), emits block sums
__global__ __launch_bounds__(256)
void scan1_kernel(const int* __restrict__ deg, int* __restrict__ row_start,
                  int* __restrict__ bsum, int n)
{
    __shared__ int ws[4];
    const int t = threadIdx.x, lane = t & 63, wid = t >> 6;
    const int base = blockIdx.x * 1024 + t * 4;
    int v0 = 0, v1 = 0, v2 = 0, v3 = 0;
    if (base + 3 < n) {
        int4 q = *reinterpret_cast<const int4*>(&deg[base]);
        v0 = q.x; v1 = q.y; v2 = q.z; v3 = q.w;
    } else {
        if (base < n)     v0 = deg[base];
        if (base + 1 < n) v1 = deg[base + 1];
        if (base + 2 < n) v2 = deg[base + 2];
        if (base + 3 < n) v3 = deg[base + 3];
    }
    int tot = v0 + v1 + v2 + v3;
    int inc = tot;
    #pragma unroll
    for (int off = 1; off < 64; off <<= 1) {
        int y = __shfl_up(inc, off);
        if (lane >= off) inc += y;
    }
    if (lane == 63) ws[wid] = inc;
    __syncthreads();
    int woff = 0;
    for (int w = 0; w < wid; ++w) woff += ws[w];
    int excl = woff + inc - tot;
    if (base < n)     row_start[base]     = excl;
    if (base + 1 < n) row_start[base + 1] = excl + v0;
    if (base + 2 < n) row_start[base + 2] = excl + v0 + v1;
    if (base + 3 < n) row_start[base + 3] = excl + v0 + v1 + v2;
    if (t == 0) bsum[blockIdx.x] = ws[0] + ws[1] + ws[2] + ws[3];
}

// apply block offsets (prefix computed in-block: SB small); derive cursor, dinv, row_start[n]
__global__ __launch_bounds__(256)
void scan3_kernel(const int* __restrict__ deg, const int* __restrict__ bsum,
                  int* __restrict__ row_start, int* __restrict__ cursor,
                  float* __restrict__ dinv, int n, int E)
{
    __shared__ int boff_s;
    const int K = blockIdx.x >> 2;          // 256-thread block spans 1/4 of a 1024-chunk
    if (threadIdx.x == 0) {
        int s = 0;
        for (int j = 0; j < K; ++j) s += bsum[j];
        boff_s = s;
    }
    __syncthreads();
    int i = blockIdx.x * 256 + threadIdx.x;
    if (i < n) {
        int rs = row_start[i] + boff_s;
        row_start[i] = rs;
        cursor[i] = rs;
        int d = deg[i];
        dinv[i] = (d > 0) ? rsqrtf((float)d) : 0.f;
    }
    if (i == 0) row_start[n] = E;
}

__global__ void fill_kernel(const int* __restrict__ src, const int* __restrict__ dst,
                            int* __restrict__ cursor, int* __restrict__ csr_src, int E)
{
    int e = blockIdx.x * blockDim.x + threadIdx.x;
    if (e < E) {
        int d = dst[e];
        int pos = atomicAdd(&cursor[d], 1);
        csr_src[pos] = src[e];
    }
}

// ===== fused: GCN gather + attention + beta gate + combine + LayerNorm1 =====
// pack: [N][384] BYTES fp8 = k(128) | v(128) | xw(128). 4 edges/wave:
// slot = lane>>4 (edge), li = lane&15 (8 dims each). No online max (|alpha| << 1).
__global__ __launch_bounds__(256)
void edge_fused_kernel(const uchar_t* __restrict__ pack,
                       const ushort_t* __restrict__ qbf,
                       const ushort_t* __restrict__ xrbf,
                       const int* __restrict__ row_start,
                       const int* __restrict__ csr_src,
                       const float* __restrict__ dinv,
                       const float* __restrict__ b_gcn,
                       const float* __restrict__ w_beta,
                       const float* __restrict__ g1, const float* __restrict__ b1,
                       const float* __restrict__ local_w, const float* __restrict__ global_w,
                       ushort_t* __restrict__ hln_bf, int n)
{
    const int wid = threadIdx.x >> 6, lane = threadIdx.x & 63;
    const int node = blockIdx.x * 4 + wid;
    if (node >= n) return;
    const int slot = lane >> 4, li = lane & 15;
    const int d8 = li * 8;

    uint4 qu = *reinterpret_cast<const uint4*>(&qbf[(size_t)node * 128 + d8]);
    float q[8];
    #pragma unroll
    for (int i = 0; i < 8; ++i) q[i] = bfp(qu, i);

    const int e0 = row_start[node], e1 = row_start[node + 1];
    const float dn = dinv[node];
    const float scale = 0.17677669529663687f;  // 1/sqrt(32)

    float s = 0.f, va[8] = {}, ga[8] = {};

    for (int j = e0; j < e1; j += 4) {
        const int je = j + slot;
        const bool act = je < e1;
        const int sidx = act ? csr_src[je] : 0;
        const uchar_t* prow = pack + (size_t)sidx * 384;
        uint2 ku = *reinterpret_cast<const uint2*>(prow + d8);
        uint2 vu = *reinterpret_cast<const uint2*>(prow + 128 + d8);
        uint2 xu = *reinterpret_cast<const uint2*>(prow + 256 + d8);
        float kf[8], vf[8], xf[8];
        UNPACK8_FP8(ku, kf);
        UNPACK8_FP8(vu, vf);
        UNPACK8_FP8(xu, xf);
        float p = 0.f;
        #pragma unroll
        for (int i = 0; i < 8; ++i) p = fmaf(q[i], kf[i], p);
        p += __shfl_xor(p, 1);                   // head = li>>2 : 4-lane groups
        p += __shfl_xor(p, 2);
        float wgt = act ? __expf(p * scale) : 0.f;
        float c   = act ? dn * dinv[sidx] : 0.f;
        s += wgt;
        #pragma unroll
        for (int i = 0; i < 8; ++i) {
            va[i] = fmaf(wgt, vf[i], va[i]);
            ga[i] = fmaf(c,   xf[i], ga[i]);
        }
    }
    // combine the 4 slots (butterfly over lane bits 4,5)
    #pragma unroll
    for (int off = 16; off <= 32; off <<= 1) {
        s += __shfl_xor(s, off);
        #pragma unroll
        for (int i = 0; i < 8; ++i) {
            va[i] += __shfl_xor(va[i], off);
            ga[i] += __shfl_xor(ga[i], off);
        }
    }
    const float denom = fmaxf(s, 1e-16f);        // per-head (head = li>>2)

    uint4 xru = *reinterpret_cast<const uint4*>(&xrbf[(size_t)node * 128 + d8]);
    float t[8];
    float part = 0.f;
    #pragma unroll
    for (int i = 0; i < 8; ++i) {
        float og = va[i] / denom;
        float xr = bfp(xru, i);
        float lo = ga[i] + b_gcn[d8 + i];
        part += og * w_beta[d8 + i] + xr * w_beta[128 + d8 + i]
              + (og - xr) * w_beta[256 + d8 + i];
        t[i] = lo;
        va[i] = og; ga[i] = xr;                   // reuse regs: va=og, ga=xr
    }
    #pragma unroll
    for (int off = 1; off <= 32; off <<= 1) part += __shfl_xor(part, off);
    const float beta = 1.f / (1.f + __expf(-part * 0.25f));   // 4x duplication

    const float lw = local_w[0], gw = global_w[0];
    float ssum = 0.f;
    #pragma unroll
    for (int i = 0; i < 8; ++i) {
        float go = beta * ga[i] + (1.f - beta) * va[i];
        t[i] = 2.f * (lw * t[i] + gw * go);
        ssum += t[i];
    }
    #pragma unroll
    for (int off = 1; off <= 32; off <<= 1) ssum += __shfl_xor(ssum, off);
    const float mu = ssum * (1.f / 512.f);        // 128 dims x4 duplication
    float vsum = 0.f;
    #pragma unroll
    for (int i = 0; i < 8; ++i) { float d = t[i] - mu; vsum += d * d; }
    #pragma unroll
    for (int off = 1; off <= 32; off <<= 1) vsum += __shfl_xor(vsum, off);
    const float rs = rsqrtf(vsum * (1.f / 512.f) + EPSV);

    if (slot == 0) {
        uint4 o;
        #pragma unroll
        for (int i = 0; i < 4; ++i) {
            float o0 = (t[2*i]   - mu) * rs * g1[d8 + 2*i]   + b1[d8 + 2*i];
            float o1 = (t[2*i+1] - mu) * rs * g1[d8 + 2*i+1] + b1[d8 + 2*i+1];
            (&o.x)[i] = (unsigned)f2bf(o0) | ((unsigned)f2bf(o1) << 16);
        }
        *reinterpret_cast<uint4*>(&hln_bf[(size_t)node * 128 + d8]) = o;
    }
}

// =================== launch ===================
extern "C" void kernel_launch(void* const* d_in, const int* in_sizes, int n_in,
                              void* d_out, int out_size, void* d_ws, size_t ws_size,
                              hipStream_t stream)
{
    const float* x      = (const float*)d_in[0];
    const int*   ei     = (const int*)d_in[1];
    const float* w_gcn  = (const float*)d_in[2];
    const float* b_gcn  = (const float*)d_in[3];
    const float* wq     = (const float*)d_in[4];
    const float* bq     = (const float*)d_in[5];
    const float* wk     = (const float*)d_in[6];
    const float* bk     = (const float*)d_in[7];
    const float* wv     = (const float*)d_in[8];
    const float* bv     = (const float*)d_in[9];
    const float* w_skip = (const float*)d_in[10];
    const float* b_skip = (const float*)d_in[11];
    const float* w_beta = (const float*)d_in[12];
    const float* g1     = (const float*)d_in[13];
    const float* b1     = (const float*)d_in[14];
    const float* g2     = (const float*)d_in[15];
    const float* b2     = (const float*)d_in[16];
    const float* w_rel  = (const float*)d_in[17];
    const float* w_root = (const float*)d_in[18];
    const float* lw     = (const float*)d_in[19];
    const float* gw     = (const float*)d_in[20];

    const int N = in_sizes[0] / D;
    const int E = in_sizes[1] / 2;
    const int* src = ei;
    const int* dst = ei + E;

    char* wsb = (char*)d_ws;
    size_t off = 0;
    auto alloc = [&](size_t bytes) -> void* {
        void* p = wsb + off;
        off += (bytes + 255) & ~(size_t)255;
        return p;
    };
    uchar_t*  pack_kvx = (uchar_t*)alloc((size_t)N * 384);       // k|v|xw fp8
    ushort_t* qb_bf    = (ushort_t*)alloc((size_t)N * 128 * 2);
    ushort_t* xr_bf    = (ushort_t*)alloc((size_t)N * 128 * 2);
    ushort_t* hln_bf   = (ushort_t*)alloc((size_t)N * 128 * 2);
    ushort_t* wt_all   = (ushort_t*)alloc(640 * 128 * 2);
    ushort_t* wt_rel   = (ushort_t*)alloc(256 * 128 * 2);
    ushort_t* wt_root  = (ushort_t*)alloc(128 * 256 * 2);
    float*    bias_all = (float*)alloc(640 * 4);
    int*      deg      = (int*)alloc((size_t)N * 4);
    int*      row_start= (int*)alloc((size_t)(N + 1) * 4);
    int*      cursor   = (int*)alloc((size_t)N * 4);
    int*      csr_src  = (int*)alloc((size_t)E * 4);
    float*    dinv     = (float*)alloc((size_t)N * 4);
    int*      bsum     = (int*)alloc(((size_t)(N + 1023) / 1024) * 4);

    float* out = (float*)d_out;
    const int SB = (N + 1023) / 1024;

    // ---- graph prep ----
    hipMemsetAsync(deg, 0, (size_t)N * sizeof(int), stream);
    deg_count_kernel<<<dim3((E + 255) / 256), dim3(256), 0, stream>>>(dst, deg, E);
    scan1_kernel<<<dim3(SB), dim3(256), 0, stream>>>(deg, row_start, bsum, N);
    scan3_kernel<<<dim3((N + 255) / 256), dim3(256), 0, stream>>>(
        deg, bsum, row_start, cursor, dinv, N, E);
    fill_kernel<<<dim3((E + 255) / 256), dim3(256), 0, stream>>>(src, dst, cursor, csr_src, E);

    // ---- weights ----
    pack_weights_kernel<<<dim3(579), dim3(256), 0, stream>>>(
        w_gcn, wq, wk, wv, w_skip, bq, bk, bv, b_skip, w_rel, w_root,
        wt_all, wt_rel, wt_root, bias_all);

    // ---- fused projections (reads f32 x directly; emits fp8 pack + bf16 q/xr) ----
    const int MB = (N + 127) / 128;
    proj_gemm<<<dim3(MB, 2), dim3(256), 0, stream>>>(
        x, wt_all, bias_all, pack_kvx, qb_bf, xr_bf, N);

    // ---- fused edge phase (fp8 gathers) ----
    edge_fused_kernel<<<dim3((N + 3) / 4), dim3(256), 0, stream>>>(
        pack_kvx, qb_bf, xr_bf, row_start, csr_src, dinv, b_gcn, w_beta,
        g1, b1, lw, gw, hln_bf, N);

    // ---- fused FFN + LN2 ----
    ffn_fused<<<dim3(MB), dim3(256), 0, stream>>>(
        hln_bf, wt_rel, wt_root, g2, b2, out, N);
}